// Round 3
// baseline (9100.210 us; speedup 1.0000x reference)
//
#include <hip/hip_runtime.h>
#include <hip/hip_bf16.h>

#define HID 64

// ---------------- degree / dinv ----------------
__global__ void init_deg_kernel(float* deg, int N) {
    int i = blockIdx.x * blockDim.x + threadIdx.x;
    if (i < N) deg[i] = 1.0f;  // self loop
}

__global__ void accum_deg_kernel(const int* __restrict__ ei, float* deg, int E) {
    int e = blockIdx.x * blockDim.x + threadIdx.x;
    if (e < E) atomicAdd(&deg[ei[E + e]], 1.0f);  // dst row
}

__global__ void finish_dinv_kernel(float* deg, int N) {
    int i = blockIdx.x * blockDim.x + threadIdx.x;
    if (i < N) deg[i] = rsqrtf(deg[i]);  // deg >= 1 always
}

// ---------------- g = dinv * (in @ W) ----------------
// 16 nodes per block, 256 threads: tid&63 = output feature, tid>>6 = node sub-group.
// May run IN-PLACE (in == g): each block reads only its own 16 rows, fully staged
// into LDS before the __syncthreads(), then overwrites those same rows.
template <int K>
__global__ void gemm_g_kernel(const float* __restrict__ in,
                              const float* __restrict__ W,
                              const float* __restrict__ dinv,
                              float* __restrict__ g, int N) {
    __shared__ float sW[K * HID];
    __shared__ float sIn[16 * K];
    int tid = threadIdx.x;
    for (int idx = tid; idx < K * HID; idx += 256) sW[idx] = W[idx];
    int base = blockIdx.x * 16;
    for (int idx = tid; idx < 16 * K; idx += 256) {
        int r = idx / K, c = idx % K;
        int node = base + r;
        sIn[idx] = (node < N) ? in[(long long)node * K + c] : 0.0f;
    }
    __syncthreads();
    int j = tid & 63;
    int si = tid >> 6;
#pragma unroll
    for (int u = 0; u < 4; u++) {
        int r = si * 4 + u;
        int node = base + r;
        if (node >= N) continue;
        float acc = 0.f;
#pragma unroll
        for (int k = 0; k < K; k++) acc += sIn[r * K + k] * sW[k * HID + j];
        g[(long long)node * HID + j] = dinv[node] * acc;
    }
}

// ---------------- scatter: acc[dst] += g[src]  (16 threads/edge, 4 feats each) ----------------
__global__ void scatter_kernel(const int* __restrict__ ei, const float* __restrict__ g,
                               float* __restrict__ acc, int E) {
    long long t = (long long)blockIdx.x * blockDim.x + threadIdx.x;
    if (t >= (long long)E * 16) return;
    int e = (int)(t >> 4);
    int r = (int)(t & 15);
    int s = ei[e];
    int d = ei[E + e];
    const float4 v = *(const float4*)&g[(long long)s * HID + r * 4];
    float* a = &acc[(long long)d * HID + r * 4];
    atomicAdd(a + 0, v.x);
    atomicAdd(a + 1, v.y);
    atomicAdd(a + 2, v.z);
    atomicAdd(a + 3, v.w);
}

// ---------------- h = relu(dinv*(acc+g) + b), written in place over g ----------------
__global__ void combine_kernel(const float* __restrict__ acc, float* __restrict__ g,
                               const float* __restrict__ dinv, const float* __restrict__ b,
                               int N) {
    long long t = (long long)blockIdx.x * blockDim.x + threadIdx.x;
    if (t >= (long long)N * HID) return;
    int j = (int)(t & 63);
    int i = (int)(t >> 6);
    float v = dinv[i] * (acc[t] + g[t]) + b[j];
    g[t] = v > 0.f ? v : 0.f;
}

// ---------------- pooling ----------------
__global__ void pool_kernel(const float* __restrict__ h, const int* __restrict__ batch,
                            float* __restrict__ sums, float* __restrict__ cnt, int N) {
    long long t = (long long)blockIdx.x * blockDim.x + threadIdx.x;
    if (t >= (long long)N * HID) return;
    int i = (int)(t >> 6);
    int j = (int)(t & 63);
    int b = batch[i];
    atomicAdd(&sums[b * HID + j], h[t]);
    if (j == 0) atomicAdd(&cnt[b], 1.0f);
}

// ---------------- final MLP head: 1 block, 128 threads (one per graph) ----------------
__global__ void final_kernel(const float* __restrict__ sums, const float* __restrict__ cnt,
                             const float* __restrict__ Wf1, const float* __restrict__ bf1,
                             const float* __restrict__ Wf2, const float* __restrict__ bf2,
                             float* __restrict__ out) {
    __shared__ float sW1[HID * 32];
    __shared__ float sW2[32];
    int tid = threadIdx.x;
    for (int idx = tid; idx < HID * 32; idx += 128) sW1[idx] = Wf1[idx];
    if (tid < 32) sW2[tid] = Wf2[tid];
    __syncthreads();
    int b = tid;  // 128 graphs, 128 threads
    float pooled[HID];
    float c = fmaxf(cnt[b], 1.0f);
#pragma unroll
    for (int j = 0; j < HID; j++) pooled[j] = sums[b * HID + j] / c;
    float o = bf2[0];
#pragma unroll 4
    for (int hd = 0; hd < 32; hd++) {
        float z = bf1[hd];
#pragma unroll
        for (int j = 0; j < HID; j++) z += pooled[j] * sW1[j * 32 + hd];
        z = fmaxf(z, 0.f);
        o += z * sW2[hd];
    }
    out[b] = o;
}

extern "C" void kernel_launch(void* const* d_in, const int* in_sizes, int n_in,
                              void* d_out, int out_size, void* d_ws, size_t ws_size,
                              hipStream_t stream) {
    const float* x     = (const float*)d_in[0];
    const int*   ei    = (const int*)d_in[1];
    // d_in[2] = edge_attr (unused by the reference)
    const int*   batch = (const int*)d_in[3];
    const float* W1  = (const float*)d_in[4];
    const float* b1  = (const float*)d_in[5];
    const float* W2  = (const float*)d_in[6];
    const float* b2  = (const float*)d_in[7];
    const float* W3  = (const float*)d_in[8];
    const float* b3  = (const float*)d_in[9];
    const float* Wf1 = (const float*)d_in[10];
    const float* bf1 = (const float*)d_in[11];
    const float* Wf2 = (const float*)d_in[12];
    const float* bf2 = (const float*)d_in[13];
    float* out = (float*)d_out;

    const int N = in_sizes[0] / 16;   // 100000
    const int E = in_sizes[1] / 2;    // 3200000

    // workspace layout — ~52 MB total
    char* ws = (char*)d_ws;
    size_t o = 0;
    float* dinv = (float*)(ws + o); o += ((size_t)N * 4 + 4095) / 4096 * 4096;
    float* acc  = (float*)(ws + o); o += (size_t)N * HID * 4;   // 25.6 MB
    float* g    = (float*)(ws + o); o += (size_t)N * HID * 4;   // 25.6 MB
    float* sums = (float*)(ws + o); o += 128 * HID * 4;
    float* cnt  = (float*)(ws + o); o += 128 * 4;
    (void)ws_size;

    const int T = 256;
    const int gN   = (N + T - 1) / T;
    const int gE   = (E + T - 1) / T;
    const int gNH  = (int)(((long long)N * HID + T - 1) / T);
    const long long scatter_work = (long long)E * 16;
    const int gSc  = (int)((scatter_work + T - 1) / T);
    const size_t acc_bytes = (size_t)N * HID * 4;

    // degrees -> dinv (in place)
    init_deg_kernel<<<gN, T, 0, stream>>>(dinv, N);
    accum_deg_kernel<<<gE, T, 0, stream>>>(ei, dinv, E);
    finish_dinv_kernel<<<gN, T, 0, stream>>>(dinv, N);

    // ---- layer 1: x(K=16) -> g ----
    hipMemsetAsync(acc, 0, acc_bytes, stream);
    gemm_g_kernel<16><<<(N + 15) / 16, T, 0, stream>>>(x, W1, dinv, g, N);
    scatter_kernel<<<gSc, T, 0, stream>>>(ei, g, acc, E);
    combine_kernel<<<gNH, T, 0, stream>>>(acc, g, dinv, b1, N);

    // ---- layer 2: g(K=64) -> g (in-place) ----
    hipMemsetAsync(acc, 0, acc_bytes, stream);
    gemm_g_kernel<64><<<(N + 15) / 16, T, 0, stream>>>(g, W2, dinv, g, N);
    scatter_kernel<<<gSc, T, 0, stream>>>(ei, g, acc, E);
    combine_kernel<<<gNH, T, 0, stream>>>(acc, g, dinv, b2, N);

    // ---- layer 3 ----
    hipMemsetAsync(acc, 0, acc_bytes, stream);
    gemm_g_kernel<64><<<(N + 15) / 16, T, 0, stream>>>(g, W3, dinv, g, N);
    scatter_kernel<<<gSc, T, 0, stream>>>(ei, g, acc, E);
    combine_kernel<<<gNH, T, 0, stream>>>(acc, g, dinv, b3, N);

    // ---- pool + head ----
    hipMemsetAsync(sums, 0, (128 * HID + 128) * 4, stream);
    pool_kernel<<<gNH, T, 0, stream>>>(g, batch, sums, cnt, N);
    final_kernel<<<1, 128, 0, stream>>>(sums, cnt, Wf1, bf1, Wf2, bf2, out);
}

// Round 4
// 1916.922 us; speedup vs baseline: 4.7473x; 4.7473x over previous
//
#include <hip/hip_runtime.h>
#include <hip/hip_bf16.h>

#define HID 64

// ================= CSR build =================

__global__ void hist_kernel(const int* __restrict__ ei, int* __restrict__ deg, int E) {
    int e = blockIdx.x * blockDim.x + threadIdx.x;
    if (e < E) atomicAdd(&deg[ei[E + e]], 1);  // dst row
}

__global__ void dinv_kernel(const int* __restrict__ deg, float* __restrict__ dinv, int N) {
    int i = blockIdx.x * blockDim.x + threadIdx.x;
    if (i < N) dinv[i] = rsqrtf((float)(deg[i] + 1));  // +1 self loop
}

// single-block exclusive scan of deg[0..N) -> row_ptr[0..N]
__global__ void scan_kernel(const int* __restrict__ deg, int* __restrict__ row_ptr, int N) {
    __shared__ int ssum[256];
    int tid = threadIdx.x;
    int C = (N + 255) / 256;
    int lo = tid * C, hi = min(lo + C, N);
    int s = 0;
    for (int i = lo; i < hi; i++) s += deg[i];
    ssum[tid] = s;
    __syncthreads();
    // Hillis-Steele inclusive scan on ssum
    for (int off = 1; off < 256; off <<= 1) {
        int v = (tid >= off) ? ssum[tid - off] : 0;
        __syncthreads();
        ssum[tid] += v;
        __syncthreads();
    }
    int run = (tid == 0) ? 0 : ssum[tid - 1];  // exclusive prefix for this chunk
    for (int i = lo; i < hi; i++) {
        row_ptr[i] = run;
        run += deg[i];
    }
    if (hi == N && lo <= N) row_ptr[N] = run;
}

__global__ void copy_int_kernel(const int* __restrict__ src, int* __restrict__ dst, int N) {
    int i = blockIdx.x * blockDim.x + threadIdx.x;
    if (i < N) dst[i] = src[i];
}

__global__ void fill_kernel(const int* __restrict__ ei, int* __restrict__ cursor,
                            int* __restrict__ col, int E) {
    int e = blockIdx.x * blockDim.x + threadIdx.x;
    if (e >= E) return;
    int s = ei[e];
    int d = ei[E + e];
    int pos = atomicAdd(&cursor[d], 1);
    col[pos] = s;
}

// ================= g = dinv * (in @ W) =================
// 16 nodes per block, 256 threads. In-place safe (block-local rows staged to LDS).
template <int K>
__global__ void gemm_g_kernel(const float* __restrict__ in,
                              const float* __restrict__ W,
                              const float* __restrict__ dinv,
                              float* __restrict__ g, int N) {
    __shared__ float sW[K * HID];
    __shared__ float sIn[16 * K];
    int tid = threadIdx.x;
    for (int idx = tid; idx < K * HID; idx += 256) sW[idx] = W[idx];
    int base = blockIdx.x * 16;
    for (int idx = tid; idx < 16 * K; idx += 256) {
        int r = idx / K, c = idx % K;
        int node = base + r;
        sIn[idx] = (node < N) ? in[(long long)node * K + c] : 0.0f;
    }
    __syncthreads();
    int j = tid & 63;
    int si = tid >> 6;
#pragma unroll
    for (int u = 0; u < 4; u++) {
        int r = si * 4 + u;
        int node = base + r;
        if (node >= N) continue;
        float acc = 0.f;
#pragma unroll
        for (int k = 0; k < K; k++) acc += sIn[r * K + k] * sW[k * HID + j];
        g[(long long)node * HID + j] = dinv[node] * acc;
    }
}

// ================= gather + combine: h[d] = relu(dinv[d]*(g[d] + sum_in g[s]) + b) =================
// one wave per dst node, lane = feature
__global__ void gather_kernel(const int* __restrict__ row_ptr, const int* __restrict__ col,
                              const float* __restrict__ g, const float* __restrict__ dinv,
                              const float* __restrict__ b, float* __restrict__ h, int N) {
    int node = blockIdx.x * 4 + (threadIdx.x >> 6);
    int lane = threadIdx.x & 63;
    if (node >= N) return;
    int beg = row_ptr[node], end = row_ptr[node + 1];
    float sum = g[(long long)node * HID + lane];  // self loop
    for (int e0 = beg; e0 < end; e0 += 64) {
        int myE = e0 + lane;
        int cs = (myE < end) ? col[myE] : 0;
        int cnt = min(64, end - e0);
        for (int j = 0; j < cnt; j++) {
            int s = __shfl(cs, j);
            sum += g[(long long)s * HID + lane];
        }
    }
    float v = dinv[node] * sum + b[lane];
    h[(long long)node * HID + lane] = v > 0.f ? v : 0.f;
}

// ================= pooling =================
__global__ void pool_kernel(const float* __restrict__ h, const int* __restrict__ batch,
                            float* __restrict__ sums, float* __restrict__ cnt, int N) {
    long long t = (long long)blockIdx.x * blockDim.x + threadIdx.x;
    if (t >= (long long)N * HID) return;
    int i = (int)(t >> 6);
    int j = (int)(t & 63);
    int b = batch[i];
    atomicAdd(&sums[b * HID + j], h[t]);
    if (j == 0) atomicAdd(&cnt[b], 1.0f);
}

// ================= final MLP head =================
__global__ void final_kernel(const float* __restrict__ sums, const float* __restrict__ cnt,
                             const float* __restrict__ Wf1, const float* __restrict__ bf1,
                             const float* __restrict__ Wf2, const float* __restrict__ bf2,
                             float* __restrict__ out) {
    __shared__ float sW1[HID * 32];
    __shared__ float sW2[32];
    int tid = threadIdx.x;
    for (int idx = tid; idx < HID * 32; idx += 128) sW1[idx] = Wf1[idx];
    if (tid < 32) sW2[tid] = Wf2[tid];
    __syncthreads();
    int b = tid;
    float pooled[HID];
    float c = fmaxf(cnt[b], 1.0f);
#pragma unroll
    for (int j = 0; j < HID; j++) pooled[j] = sums[b * HID + j] / c;
    float o = bf2[0];
#pragma unroll 4
    for (int hd = 0; hd < 32; hd++) {
        float z = bf1[hd];
#pragma unroll
        for (int j = 0; j < HID; j++) z += pooled[j] * sW1[j * 32 + hd];
        z = fmaxf(z, 0.f);
        o += z * sW2[hd];
    }
    out[b] = o;
}

extern "C" void kernel_launch(void* const* d_in, const int* in_sizes, int n_in,
                              void* d_out, int out_size, void* d_ws, size_t ws_size,
                              hipStream_t stream) {
    const float* x     = (const float*)d_in[0];
    const int*   ei    = (const int*)d_in[1];
    const int*   batch = (const int*)d_in[3];
    const float* W1  = (const float*)d_in[4];
    const float* b1  = (const float*)d_in[5];
    const float* W2  = (const float*)d_in[6];
    const float* b2  = (const float*)d_in[7];
    const float* W3  = (const float*)d_in[8];
    const float* b3  = (const float*)d_in[9];
    const float* Wf1 = (const float*)d_in[10];
    const float* bf1 = (const float*)d_in[11];
    const float* Wf2 = (const float*)d_in[12];
    const float* bf2 = (const float*)d_in[13];
    float* out = (float*)d_out;

    const int N = in_sizes[0] / 16;   // 100000
    const int E = in_sizes[1] / 2;    // 3200000

    // workspace layout (~65 MB)
    char* ws = (char*)d_ws;
    size_t o = 0;
    float* dinv    = (float*)(ws + o); o += ((size_t)N * 4 + 4095) / 4096 * 4096;
    int*   row_ptr = (int*)(ws + o);   o += ((size_t)(N + 1) * 4 + 4095) / 4096 * 4096;
    int*   col     = (int*)(ws + o);   o += (size_t)E * 4;            // 12.8 MB
    float* A       = (float*)(ws + o); o += (size_t)N * HID * 4;      // 25.6 MB
    float* B       = (float*)(ws + o); o += (size_t)N * HID * 4;      // 25.6 MB
    float* sums    = (float*)(ws + o); o += 128 * HID * 4;
    float* cnt     = (float*)(ws + o); o += 128 * 4;
    (void)ws_size;
    int* deg_i  = (int*)B;  // transient: histogram before B is needed
    int* cursor = (int*)A;  // transient: fill cursors before A is needed

    const int T = 256;
    const int gN  = (N + T - 1) / T;
    const int gE  = (E + T - 1) / T;
    const int gNH = (int)(((long long)N * HID + T - 1) / T);
    const int gGa = (N + 3) / 4;
    const int gGm = (N + 15) / 16;

    // ---- CSR build (counting sort by dst) ----
    hipMemsetAsync(deg_i, 0, (size_t)N * 4, stream);
    hist_kernel<<<gE, T, 0, stream>>>(ei, deg_i, E);
    dinv_kernel<<<gN, T, 0, stream>>>(deg_i, dinv, N);
    scan_kernel<<<1, 256, 0, stream>>>(deg_i, row_ptr, N);
    copy_int_kernel<<<gN, T, 0, stream>>>(row_ptr, cursor, N);
    fill_kernel<<<gE, T, 0, stream>>>(ei, cursor, col, E);

    // ---- layer 1: x(K=16) -> A -> gather -> B ----
    gemm_g_kernel<16><<<gGm, T, 0, stream>>>(x, W1, dinv, A, N);
    gather_kernel<<<gGa, T, 0, stream>>>(row_ptr, col, A, dinv, b1, B, N);

    // ---- layer 2: B -> B (in-place gemm) -> gather -> A ----
    gemm_g_kernel<64><<<gGm, T, 0, stream>>>(B, W2, dinv, B, N);
    gather_kernel<<<gGa, T, 0, stream>>>(row_ptr, col, B, dinv, b2, A, N);

    // ---- layer 3: A -> A -> gather -> B ----
    gemm_g_kernel<64><<<gGm, T, 0, stream>>>(A, W3, dinv, A, N);
    gather_kernel<<<gGa, T, 0, stream>>>(row_ptr, col, A, dinv, b3, B, N);

    // ---- pool + head ----
    hipMemsetAsync(sums, 0, (128 * HID + 128) * 4, stream);
    pool_kernel<<<gNH, T, 0, stream>>>(B, batch, sums, cnt, N);
    final_kernel<<<1, 128, 0, stream>>>(sums, cnt, Wf1, bf1, Wf2, bf2, out);
}

// Round 5
// 1339.356 us; speedup vs baseline: 6.7945x; 1.4312x over previous
//
#include <hip/hip_runtime.h>
#include <hip/hip_bf16.h>

#define HID 64

// ================= CSR build =================

__global__ void hist_kernel(const int* __restrict__ ei, int* __restrict__ deg, int E) {
    int e = blockIdx.x * blockDim.x + threadIdx.x;
    if (e < E) atomicAdd(&deg[ei[E + e]], 1);  // dst row
}

__global__ void dinv_kernel(const int* __restrict__ deg, float* __restrict__ dinv, int N) {
    int i = blockIdx.x * blockDim.x + threadIdx.x;
    if (i < N) dinv[i] = rsqrtf((float)(deg[i] + 1));  // +1 self loop
}

// single-block exclusive scan of deg[0..N) -> row_ptr[0..N]
__global__ void scan_kernel(const int* __restrict__ deg, int* __restrict__ row_ptr, int N) {
    __shared__ int ssum[256];
    int tid = threadIdx.x;
    int C = (N + 255) / 256;
    int lo = tid * C, hi = min(lo + C, N);
    int s = 0;
    for (int i = lo; i < hi; i++) s += deg[i];
    ssum[tid] = s;
    __syncthreads();
    for (int off = 1; off < 256; off <<= 1) {
        int v = (tid >= off) ? ssum[tid - off] : 0;
        __syncthreads();
        ssum[tid] += v;
        __syncthreads();
    }
    int run = (tid == 0) ? 0 : ssum[tid - 1];
    for (int i = lo; i < hi; i++) {
        row_ptr[i] = run;
        run += deg[i];
    }
    if (hi == N && lo <= N) row_ptr[N] = run;
}

__global__ void copy_int_kernel(const int* __restrict__ src, int* __restrict__ dst, int N) {
    int i = blockIdx.x * blockDim.x + threadIdx.x;
    if (i < N) dst[i] = src[i];
}

__global__ void fill_kernel(const int* __restrict__ ei, int* __restrict__ cursor,
                            int* __restrict__ col, int E) {
    int e = blockIdx.x * blockDim.x + threadIdx.x;
    if (e >= E) return;
    int s = ei[e];
    int d = ei[E + e];
    int pos = atomicAdd(&cursor[d], 1);
    col[pos] = s;
}

// ================= g = dinv * (in @ W) =================
// 16 nodes per block, 256 threads. In-place safe (block-local rows staged to LDS).
template <int K>
__global__ void gemm_g_kernel(const float* __restrict__ in,
                              const float* __restrict__ W,
                              const float* __restrict__ dinv,
                              float* __restrict__ g, int N) {
    __shared__ float sW[K * HID];
    __shared__ float sIn[16 * K];
    int tid = threadIdx.x;
    for (int idx = tid; idx < K * HID; idx += 256) sW[idx] = W[idx];
    int base = blockIdx.x * 16;
    for (int idx = tid; idx < 16 * K; idx += 256) {
        int r = idx / K, c = idx % K;
        int node = base + r;
        sIn[idx] = (node < N) ? in[(long long)node * K + c] : 0.0f;
    }
    __syncthreads();
    int j = tid & 63;
    int si = tid >> 6;
#pragma unroll
    for (int u = 0; u < 4; u++) {
        int r = si * 4 + u;
        int node = base + r;
        if (node >= N) continue;
        float acc = 0.f;
#pragma unroll
        for (int k = 0; k < K; k++) acc += sIn[r * K + k] * sW[k * HID + j];
        g[(long long)node * HID + j] = dinv[node] * acc;
    }
}

// ================= gather + combine: h[d] = relu(dinv[d]*(g[d] + sum_in g[s]) + b) =================
// one wave per dst node, lane = feature
__global__ void gather_kernel(const int* __restrict__ row_ptr, const int* __restrict__ col,
                              const float* __restrict__ g, const float* __restrict__ dinv,
                              const float* __restrict__ b, float* __restrict__ h, int N) {
    int node = blockIdx.x * 4 + (threadIdx.x >> 6);
    int lane = threadIdx.x & 63;
    if (node >= N) return;
    int beg = row_ptr[node], end = row_ptr[node + 1];
    float sum = g[(long long)node * HID + lane];  // self loop
    for (int e0 = beg; e0 < end; e0 += 64) {
        int myE = e0 + lane;
        int cs = (myE < end) ? col[myE] : 0;
        int cnt = min(64, end - e0);
        for (int j = 0; j < cnt; j++) {
            int s = __shfl(cs, j);
            sum += g[(long long)s * HID + lane];
        }
    }
    float v = dinv[node] * sum + b[lane];
    h[(long long)node * HID + lane] = v > 0.f ? v : 0.f;
}

// ================= pooling: segmented reduction (batch is sorted) =================
// one wave per 64-node contiguous chunk; lane = feature; flush on graph-id change.
__global__ void pool_kernel(const float* __restrict__ h, const int* __restrict__ batch,
                            float* __restrict__ sums, float* __restrict__ cnt, int N) {
    int wave = blockIdx.x * 4 + (threadIdx.x >> 6);
    int lane = threadIdx.x & 63;
    int lo = wave * 64;
    if (lo >= N) return;
    int hi = min(lo + 64, N);
    int curb = batch[lo];
    float sum = 0.f;
    int nseg = 0;
    for (int i = lo; i < hi; i++) {
        int b = batch[i];
        if (b != curb) {
            atomicAdd(&sums[curb * HID + lane], sum);
            if (lane == 0) atomicAdd(&cnt[curb], (float)nseg);
            curb = b; sum = 0.f; nseg = 0;
        }
        sum += h[(long long)i * HID + lane];
        nseg++;
    }
    atomicAdd(&sums[curb * HID + lane], sum);
    if (lane == 0) atomicAdd(&cnt[curb], (float)nseg);
}

// ================= final MLP head =================
__global__ void final_kernel(const float* __restrict__ sums, const float* __restrict__ cnt,
                             const float* __restrict__ Wf1, const float* __restrict__ bf1,
                             const float* __restrict__ Wf2, const float* __restrict__ bf2,
                             float* __restrict__ out) {
    __shared__ float sW1[HID * 32];
    __shared__ float sW2[32];
    int tid = threadIdx.x;
    for (int idx = tid; idx < HID * 32; idx += 128) sW1[idx] = Wf1[idx];
    if (tid < 32) sW2[tid] = Wf2[tid];
    __syncthreads();
    int b = tid;
    float pooled[HID];
    float c = fmaxf(cnt[b], 1.0f);
#pragma unroll
    for (int j = 0; j < HID; j++) pooled[j] = sums[b * HID + j] / c;
    float o = bf2[0];
#pragma unroll 4
    for (int hd = 0; hd < 32; hd++) {
        float z = bf1[hd];
#pragma unroll
        for (int j = 0; j < HID; j++) z += pooled[j] * sW1[j * 32 + hd];
        z = fmaxf(z, 0.f);
        o += z * sW2[hd];
    }
    out[b] = o;
}

extern "C" void kernel_launch(void* const* d_in, const int* in_sizes, int n_in,
                              void* d_out, int out_size, void* d_ws, size_t ws_size,
                              hipStream_t stream) {
    const float* x     = (const float*)d_in[0];
    const int*   ei    = (const int*)d_in[1];
    const int*   batch = (const int*)d_in[3];
    const float* W1  = (const float*)d_in[4];
    const float* b1  = (const float*)d_in[5];
    const float* W2  = (const float*)d_in[6];
    const float* b2  = (const float*)d_in[7];
    const float* W3  = (const float*)d_in[8];
    const float* b3  = (const float*)d_in[9];
    const float* Wf1 = (const float*)d_in[10];
    const float* bf1 = (const float*)d_in[11];
    const float* Wf2 = (const float*)d_in[12];
    const float* bf2 = (const float*)d_in[13];
    float* out = (float*)d_out;

    const int N = in_sizes[0] / 16;   // 100000
    const int E = in_sizes[1] / 2;    // 3200000

    // workspace layout (~65 MB)
    char* ws = (char*)d_ws;
    size_t o = 0;
    float* dinv    = (float*)(ws + o); o += ((size_t)N * 4 + 4095) / 4096 * 4096;
    int*   row_ptr = (int*)(ws + o);   o += ((size_t)(N + 1) * 4 + 4095) / 4096 * 4096;
    int*   col     = (int*)(ws + o);   o += (size_t)E * 4;            // 12.8 MB
    float* A       = (float*)(ws + o); o += (size_t)N * HID * 4;      // 25.6 MB
    float* B       = (float*)(ws + o); o += (size_t)N * HID * 4;      // 25.6 MB
    float* sums    = (float*)(ws + o); o += 128 * HID * 4;
    float* cnt     = (float*)(ws + o); o += 128 * 4;
    (void)ws_size;
    int* deg_i  = (int*)B;  // transient: histogram before B is needed
    int* cursor = (int*)A;  // transient: fill cursors before A is needed

    const int T = 256;
    const int gN  = (N + T - 1) / T;
    const int gE  = (E + T - 1) / T;
    const int gGa = (N + 3) / 4;
    const int gGm = (N + 15) / 16;
    const int gPool = ((N + 63) / 64 + 3) / 4;

    // ---- CSR build (counting sort by dst) ----
    hipMemsetAsync(deg_i, 0, (size_t)N * 4, stream);
    hist_kernel<<<gE, T, 0, stream>>>(ei, deg_i, E);
    dinv_kernel<<<gN, T, 0, stream>>>(deg_i, dinv, N);
    scan_kernel<<<1, 256, 0, stream>>>(deg_i, row_ptr, N);
    copy_int_kernel<<<gN, T, 0, stream>>>(row_ptr, cursor, N);
    fill_kernel<<<gE, T, 0, stream>>>(ei, cursor, col, E);

    // ---- layer 1: x(K=16) -> A -> gather -> B ----
    gemm_g_kernel<16><<<gGm, T, 0, stream>>>(x, W1, dinv, A, N);
    gather_kernel<<<gGa, T, 0, stream>>>(row_ptr, col, A, dinv, b1, B, N);

    // ---- layer 2: B -> B (in-place gemm) -> gather -> A ----
    gemm_g_kernel<64><<<gGm, T, 0, stream>>>(B, W2, dinv, B, N);
    gather_kernel<<<gGa, T, 0, stream>>>(row_ptr, col, B, dinv, b2, A, N);

    // ---- layer 3: A -> A -> gather -> B ----
    gemm_g_kernel<64><<<gGm, T, 0, stream>>>(A, W3, dinv, A, N);
    gather_kernel<<<gGa, T, 0, stream>>>(row_ptr, col, A, dinv, b3, B, N);

    // ---- pool + head ----
    hipMemsetAsync(sums, 0, (128 * HID + 128) * 4, stream);
    pool_kernel<<<gPool, T, 0, stream>>>(B, batch, sums, cnt, N);
    final_kernel<<<1, 128, 0, stream>>>(sums, cnt, Wf1, bf1, Wf2, bf2, out);
}